// Round 3
// baseline (14453.883 us; speedup 1.0000x reference)
//
#include <hip/hip_runtime.h>
#include <cstdint>
#include <cstddef>

#define B    32
#define E    512
#define HD   1024
#define V    32000
#define TMAX 64
#define NBLK 250          // k_logits blocks: 32000 / 128
#define THREEFRY_PARTITIONABLE 1   // JAX >= 0.4.36 default; flip to 0 if captions mismatch

// ---------------- Threefry-2x32 (exact JAX semantics) ----------------
__host__ __device__ __forceinline__ void tf2x32(uint32_t k0, uint32_t k1,
                                                uint32_t x0, uint32_t x1,
                                                uint32_t &o0, uint32_t &o1) {
  uint32_t ks2 = k0 ^ k1 ^ 0x1BD11BDAu;
#define TF_R(x, r) (((x) << (r)) | ((x) >> (32 - (r))))
#define TF_G(a, b, c, d)                         \
  x0 += x1; x1 = TF_R(x1, a); x1 ^= x0;          \
  x0 += x1; x1 = TF_R(x1, b); x1 ^= x0;          \
  x0 += x1; x1 = TF_R(x1, c); x1 ^= x0;          \
  x0 += x1; x1 = TF_R(x1, d); x1 ^= x0;
  x0 += k0; x1 += k1;
  TF_G(13, 15, 26, 6)  x0 += k1;  x1 += ks2 + 1u;
  TF_G(17, 29, 16, 24) x0 += ks2; x1 += k0 + 2u;
  TF_G(13, 15, 26, 6)  x0 += k0;  x1 += k1 + 3u;
  TF_G(17, 29, 16, 24) x0 += k1;  x1 += ks2 + 4u;
  TF_G(13, 15, 26, 6)  x0 += ks2; x1 += k0 + 5u;
  o0 = x0; o1 = x1;
#undef TF_G
#undef TF_R
}

__device__ __forceinline__ uint32_t random_bits_elem(uint32_t fk0, uint32_t fk1, uint32_t i) {
#if THREEFRY_PARTITIONABLE
  uint32_t o0, o1;
  tf2x32(fk0, fk1, 0u, i, o0, o1);       // counts = iota(u64): hi=0, lo=i
  return o0 ^ o1;
#else
  const uint32_t half = (uint32_t)(B * V) / 2u;  // 512000
  uint32_t o0, o1;
  if (i < half) { tf2x32(fk0, fk1, i, i + half, o0, o1); return o0; }
  else          { tf2x32(fk0, fk1, i - half, i, o0, o1); return o1; }
#endif
}

__device__ __forceinline__ float gumbel_from_u32(uint32_t bits) {
  uint32_t fb = (bits >> 9) | 0x3f800000u;            // exponent of 1.0, random mantissa
  float u = __uint_as_float(fb) - 1.0f;               // [0, 1)
  const float tiny = 1.17549435e-38f;                 // FLT_MIN (jax uniform minval)
  u = fmaxf(tiny, u + tiny);                          // == max(tiny, u*(1-tiny)+tiny) in fp32
  float a = logf(u);
  return -logf(-a);
}

// XLA logistic expansion: 0.5 + 0.5 * tanh(0.5 * x); use non-contracted ops
__device__ __forceinline__ float sigx(float x) {
  return __fadd_rn(__fmul_rn(0.5f, tanhf(__fmul_rn(0.5f, x))), 0.5f);
}

// ---------------- init: h0 = cond@Wh^T+bh, c0 = cond@Wc^T+bc, tok=1 ----------------
extern "C" __global__ __launch_bounds__(256)
void k_init(const float* __restrict__ cond,
            const float* __restrict__ Wh, const float* __restrict__ bh,
            const float* __restrict__ Wc, const float* __restrict__ bc,
            float* __restrict__ h0, float* __restrict__ c0, int* __restrict__ tok) {
  __shared__ float smem[8192];                 // 32 KB: cond chunk (32x256), then partials
  float4* sm4 = (float4*)smem;
  const int tid = threadIdx.x;
  const int bk  = blockIdx.x;                  // 64 blocks x 32 cols = 2048 cols (h0|c0)
  const int s = tid >> 5, c = tid & 31;
  const int gcol = bk * 32 + c;
  const float* Wmat = (gcol < HD) ? Wh : Wc;
  const int mcol = gcol & (HD - 1);
  float acc[32];
#pragma unroll
  for (int r = 0; r < 32; ++r) acc[r] = 0.f;

  for (int cc = 0; cc < 2; ++cc) {
    const int kb4 = cc * 64;                   // float4 offset within K=512 row
    for (int i = tid; i < 2048; i += 256) {
      int r = i >> 6, k4 = i & 63;
      sm4[i] = ((const float4*)cond)[(size_t)r * 128 + kb4 + k4];
    }
    __syncthreads();
    const float4* W4 = (const float4*)Wmat + (size_t)mcol * 128 + kb4;
#pragma unroll
    for (int kk = 0; kk < 8; ++kk) {
      int k4 = s * 8 + kk;
      float4 w = W4[k4];
#pragma unroll
      for (int r = 0; r < 32; ++r) {
        float4 xv = sm4[r * 64 + k4];
        acc[r] = fmaf(w.x, xv.x, acc[r]);
        acc[r] = fmaf(w.y, xv.y, acc[r]);
        acc[r] = fmaf(w.z, xv.z, acc[r]);
        acc[r] = fmaf(w.w, xv.w, acc[r]);
      }
    }
    __syncthreads();
  }
#pragma unroll
  for (int r = 0; r < 32; ++r) smem[r * 256 + tid] = acc[r];   // [r][s*32+c]
  __syncthreads();
  for (int q = 0; q < 4; ++q) {
    int o = tid * 4 + q;
    int c_o = o >> 5, r_o = o & 31;
    float v = 0.f;
#pragma unroll
    for (int ss = 0; ss < 8; ++ss) v += smem[r_o * 256 + ss * 32 + c_o];
    int colg = bk * 32 + c_o;
    v += (colg < HD) ? bh[colg] : bc[colg - HD];
    float* dst = (colg < HD) ? h0 : c0;
    dst[r_o * HD + (colg & (HD - 1))] = v;
  }
  if (bk == 0 && tid < B) tok[tid] = 1;        // START_TOK
}

// ---------------- gates + LSTM pointwise ----------------
extern "C" __global__ __launch_bounds__(256)
void k_gates(const float* __restrict__ Wih, const float* __restrict__ bih,
             const float* __restrict__ Whh, const float* __restrict__ bhh,
             const float* __restrict__ embed, const int* __restrict__ tok,
             const float* __restrict__ h_prev, const float* __restrict__ c_prev,
             float* __restrict__ h_new, float* __restrict__ c_new) {
  __shared__ float smem[8192];                 // 32 KB chunk stage / partials / gates
  __shared__ int tokl[B];
  float4* sm4 = (float4*)smem;
  const int tid = threadIdx.x;
  const int bk  = blockIdx.x;                  // 128 blocks: hidden units j0..j0+7
  const int j0  = bk * 8;
  if (tid < B) tokl[tid] = tok[tid];
  __syncthreads();
  const int s = tid >> 5, c = tid & 31;        // 8 k-slices x 32 cols
  const int col = (c >> 3) * HD + j0 + (c & 7);  // gate*1024 + unit
  float acc[32];
#pragma unroll
  for (int r = 0; r < 32; ++r) acc[r] = 0.f;

  for (int cc = 0; cc < 6; ++cc) {             // 2 x-chunks (K=512) + 4 h-chunks (K=1024)
    const bool xpart = (cc < 2);
    const int kb4 = xpart ? cc * 64 : (cc - 2) * 64;
    for (int i = tid; i < 2048; i += 256) {
      int r = i >> 6, k4 = i & 63;
      float4 v;
      if (xpart) v = ((const float4*)embed)[(size_t)tokl[r] * 128 + kb4 + k4];
      else       v = ((const float4*)h_prev)[(size_t)r * 256 + kb4 + k4];
      sm4[i] = v;
    }
    __syncthreads();
    const float4* W4 = xpart ? ((const float4*)Wih + (size_t)col * 128 + kb4)
                             : ((const float4*)Whh + (size_t)col * 256 + kb4);
#pragma unroll
    for (int kk = 0; kk < 8; ++kk) {
      int k4 = s * 8 + kk;
      float4 w = W4[k4];
#pragma unroll
      for (int r = 0; r < 32; ++r) {
        float4 xv = sm4[r * 64 + k4];
        acc[r] = fmaf(w.x, xv.x, acc[r]);
        acc[r] = fmaf(w.y, xv.y, acc[r]);
        acc[r] = fmaf(w.z, xv.z, acc[r]);
        acc[r] = fmaf(w.w, xv.w, acc[r]);
      }
    }
    __syncthreads();
  }
#pragma unroll
  for (int r = 0; r < 32; ++r) smem[r * 256 + tid] = acc[r];
  __syncthreads();
  float red[4];
  for (int q = 0; q < 4; ++q) {
    int o = tid * 4 + q;
    int c_o = o >> 5, r_o = o & 31;
    float v = 0.f;
#pragma unroll
    for (int ss = 0; ss < 8; ++ss) v += smem[r_o * 256 + ss * 32 + c_o];
    int colg = (c_o >> 3) * HD + j0 + (c_o & 7);
    v += bih[colg] + bhh[colg];
    red[q] = v;
  }
  __syncthreads();
  for (int q = 0; q < 4; ++q) smem[tid * 4 + q] = red[q];      // gates[c_o*32 + r_o]
  __syncthreads();
  {
    int r = tid & 31, u2 = tid >> 5;           // 32 rows x 8 units
    float gi = smem[(0 * 8 + u2) * 32 + r];
    float gf = smem[(1 * 8 + u2) * 32 + r];
    float gg = smem[(2 * 8 + u2) * 32 + r];
    float go = smem[(3 * 8 + u2) * 32 + r];
    float si = sigx(gi), sf = sigx(gf), sg = tanhf(gg), so = sigx(go);
    float cp = c_prev[r * HD + j0 + u2];
    float cn = __fadd_rn(__fmul_rn(sf, cp), __fmul_rn(si, sg));
    float hn = __fmul_rn(so, tanhf(cn));
    c_new[r * HD + j0 + u2] = cn;
    h_new[r * HD + j0 + u2] = hn;
  }
}

// ---------------- logits GEMM + bias + stage write + gumbel partial argmax ----------------
extern "C" __global__ __launch_bounds__(512)
void k_logits(const float* __restrict__ Wout, const float* __restrict__ bout,
              const float* __restrict__ h,
              float* __restrict__ optr, int ostride, int ooff,
              float* __restrict__ pmax, int* __restrict__ pidx,
              uint32_t fk0, uint32_t fk1) {
  __shared__ float smem[32768];                // 128 KB: h[32][1024], then partials
  float4* sm4 = (float4*)smem;
  const int tid = threadIdx.x;
  const int bk  = blockIdx.x;                  // 250 blocks x 128 vocab cols
  for (int i = tid; i < 8192; i += 512) sm4[i] = ((const float4*)h)[i];
  __syncthreads();
  const int s = tid >> 6, l = tid & 63;        // wave = k-slice (128 k), lane = col-pair
  const int c0 = bk * 128 + l * 2;
  float a0[32], a1[32];
#pragma unroll
  for (int r = 0; r < 32; ++r) { a0[r] = 0.f; a1[r] = 0.f; }
  const float4* W0 = (const float4*)Wout + (size_t)c0 * 256;
  const float4* W1 = W0 + 256;
  const int k4lo = s * 32;
  for (int k4 = k4lo; k4 < k4lo + 32; ++k4) {
    float4 w0 = W0[k4];
    float4 w1 = W1[k4];
#pragma unroll
    for (int r = 0; r < 32; ++r) {
      float4 hv = sm4[r * 256 + k4];           // wave-uniform broadcast ds_read_b128
      a0[r] = fmaf(w0.x, hv.x, a0[r]); a1[r] = fmaf(w1.x, hv.x, a1[r]);
      a0[r] = fmaf(w0.y, hv.y, a0[r]); a1[r] = fmaf(w1.y, hv.y, a1[r]);
      a0[r] = fmaf(w0.z, hv.z, a0[r]); a1[r] = fmaf(w1.z, hv.z, a1[r]);
      a0[r] = fmaf(w0.w, hv.w, a0[r]); a1[r] = fmaf(w1.w, hv.w, a1[r]);
    }
  }
  __syncthreads();
#pragma unroll
  for (int r = 0; r < 32; ++r) {               // partials: [(cc*32+r)*512 + tid], conflict-free
    smem[r * 512 + tid]        = a0[r];
    smem[(32 + r) * 512 + tid] = a1[r];
  }
  __syncthreads();
  const int r  = tid >> 4;                     // batch row
  const int c8 = (tid & 15) * 8;               // 8 consecutive local cols
  float red[8];
  for (int q = 0; q < 8; ++q) {
    int c_loc = c8 + q;
    float v = 0.f;
#pragma unroll
    for (int ss = 0; ss < 8; ++ss)
      v += smem[((c_loc & 1) * 32 + r) * 512 + ss * 64 + (c_loc >> 1)];
    v += bout[bk * 128 + c_loc];
    red[q] = v;
  }
  const int vbase = bk * 128 + c8;
  if (ostride == 1) {                          // staged (coalesced) path
    float4* dst = (float4*)(optr + (size_t)r * V + vbase);
    dst[0] = make_float4(red[0], red[1], red[2], red[3]);
    dst[1] = make_float4(red[4], red[5], red[6], red[7]);
  } else {                                     // direct strided fallback
    for (int q = 0; q < 8; ++q)
      optr[(size_t)(r * V + vbase + q) * ostride + ooff] = red[q];
  }
  float bestv = -__builtin_inff(); int besti = 0x7fffffff;
  for (int q = 0; q < 8; ++q) {                // ascending v + strict '>' => lowest idx on tie
    uint32_t bits = random_bits_elem(fk0, fk1, (uint32_t)(r * V + vbase + q));
    float cand = red[q] + gumbel_from_u32(bits);
    if (cand > bestv) { bestv = cand; besti = vbase + q; }
  }
  for (int m = 1; m < 16; m <<= 1) {           // 16 lanes share a row
    float ov = __shfl_xor(bestv, m);
    int   oi = __shfl_xor(besti, m);
    if (ov > bestv || (ov == bestv && oi < besti)) { bestv = ov; besti = oi; }
  }
  if ((tid & 15) == 0) { pmax[r * NBLK + bk] = bestv; pidx[r * NBLK + bk] = besti; }
}

// ---------------- finalize sample ----------------
extern "C" __global__ void k_sample(const float* __restrict__ pmax, const int* __restrict__ pidx,
                                    int* __restrict__ tok, float* __restrict__ cap, int t) {
  const int tid = threadIdx.x;                 // 1024 threads: 32 rows x 32 lanes
  const int r = tid >> 5, j = tid & 31;
  float bestv = -__builtin_inff(); int besti = 0x7fffffff;
  for (int blk = j; blk < NBLK; blk += 32) {
    float v = pmax[r * NBLK + blk]; int i = pidx[r * NBLK + blk];
    if (v > bestv || (v == bestv && i < besti)) { bestv = v; besti = i; }
  }
  for (int m = 1; m < 32; m <<= 1) {
    float ov = __shfl_xor(bestv, m);
    int   oi = __shfl_xor(besti, m);
    if (ov > bestv || (ov == bestv && oi < besti)) { bestv = ov; besti = oi; }
  }
  if (j == 0) { tok[r] = besti; cap[r * TMAX + t] = (float)besti; }
}

// ---------------- transpose-flush staged logits to [B,V,T] ----------------
extern "C" __global__ void k_flush(const float* __restrict__ stage, float* __restrict__ out,
                                   int t0, int group) {
  const size_t e = (size_t)blockIdx.x * blockDim.x + threadIdx.x;   // b*V + v
  if (e >= (size_t)B * V) return;
  if (group == 16) {
    float v[16];
#pragma unroll
    for (int tt = 0; tt < 16; ++tt) v[tt] = stage[(size_t)tt * B * V + e];
    float4* o4 = (float4*)(out + e * TMAX + t0);
#pragma unroll
    for (int q = 0; q < 4; ++q)
      o4[q] = make_float4(v[q * 4], v[q * 4 + 1], v[q * 4 + 2], v[q * 4 + 3]);
  } else {
    for (int tt = 0; tt < group; ++tt)
      out[e * TMAX + t0 + tt] = stage[(size_t)tt * B * V + e];
  }
}

// ---------------- host ----------------
extern "C" void kernel_launch(void* const* d_in, const int* in_sizes, int n_in,
                              void* d_out, int out_size, void* d_ws, size_t ws_size,
                              hipStream_t stream) {
  const float* cond  = (const float*)d_in[0];
  const float* Wh    = (const float*)d_in[1];
  const float* bh    = (const float*)d_in[2];
  const float* Wc    = (const float*)d_in[3];
  const float* bc    = (const float*)d_in[4];
  const float* embed = (const float*)d_in[5];
  const float* Wih   = (const float*)d_in[6];
  const float* bih   = (const float*)d_in[7];
  const float* Whh   = (const float*)d_in[8];
  const float* bhh   = (const float*)d_in[9];
  const float* Wout  = (const float*)d_in[10];
  const float* bout  = (const float*)d_in[11];

  float* cap  = (float*)d_out;                    // captions [B][T] as float
  float* lout = cap + (size_t)B * TMAX;           // captions_logits [B][V][T]

  const size_t BV = (size_t)B * V;
  const size_t extra = ((size_t)2 * B * HD * 2 + (size_t)B * NBLK * 2 + B + 64) * 4;
  const int cands[5] = {16, 8, 4, 2, 1};
  int group = 0;
  for (int gi = 0; gi < 5; ++gi)
    if ((size_t)cands[gi] * BV * 4 + extra <= ws_size) { group = cands[gi]; break; }

  float* stage = (float*)d_ws;
  float* hbuf  = stage + (size_t)group * BV;      // h[2][B][HD]
  float* cbuf  = hbuf + 2 * B * HD;               // c[2][B][HD]
  float* pmaxb = cbuf + 2 * B * HD;               // [B][NBLK]
  int*   pidxb = (int*)(pmaxb + B * NBLK);
  int*   tokb  = (int*)(pidxb + B * NBLK);

  uint32_t fk0[TMAX], fk1[TMAX];                  // fold_in(key(42), t) on host
  for (int t = 0; t < TMAX; ++t) tf2x32(0u, 42u, 0u, (uint32_t)t, fk0[t], fk1[t]);

  k_init<<<64, 256, 0, stream>>>(cond, Wh, bh, Wc, bc, hbuf, cbuf, tokb);
  for (int t = 0; t < TMAX; ++t) {
    const int p = t & 1;
    const float* hp = hbuf + (size_t)p * B * HD;
    const float* cp = cbuf + (size_t)p * B * HD;
    float* hn = hbuf + (size_t)(1 - p) * B * HD;
    float* cn = cbuf + (size_t)(1 - p) * B * HD;
    k_gates<<<128, 256, 0, stream>>>(Wih, bih, Whh, bhh, embed, tokb, hp, cp, hn, cn);
    float* optr; int ostride, ooff;
    if (group > 0) { optr = stage + (size_t)(t % group) * BV; ostride = 1; ooff = 0; }
    else           { optr = lout; ostride = TMAX; ooff = t; }
    k_logits<<<NBLK, 512, 0, stream>>>(Wout, bout, hn, optr, ostride, ooff,
                                       pmaxb, pidxb, fk0[t], fk1[t]);
    k_sample<<<1, 1024, 0, stream>>>(pmaxb, pidxb, tokb, cap, t);
    if (group > 0 && ((t + 1) % group == 0))
      k_flush<<<(int)((BV + 255) / 256), 256, 0, stream>>>(stage, lout, t + 1 - group, group);
  }
}